// Round 6
// baseline (715.200 us; speedup 1.0000x reference)
//
#include <hip/hip_runtime.h>

// ExtractSearchWindows: out[b,h,w,rr,tt] = (uint8)Q[b, h+off+ry+ty, w+off+rx+tx],
// Q = input padded by 6; stored as INT32.
//
// R13 theory: eight nulled structural theories (drain/barrier/occupancy/duty/
// bank-conflict/vmcnt/alignment) + issue accounting (>=4x headroom everywhere)
// leave ONE variable: instantaneous write-window size. Fill (6.3 TB/s): ~2MB
// live span -> ~16KB/HBM-channel, few open rows. R3-R12 (2.9 TB/s): 768-2048
// concurrent 38.4KB group regions = 30-78MB live span -> hundreds of open rows
// per channel, write-queue reorder saturates -> ~46% efficiency. Fix: one
// group per BLOCK (8 waves share one staged patch), grid=256 -> <=256
// concurrent CONSECUTIVE groups = 9.8MB live span; block-round striping (round
// r = 8KB contiguous per block) + 2 barriers/iter phase-lock the waves ->
// each channel sees few-row clusters. Swizzled LDS gather + L2-hot offset
// table with 1-round prefetch kept; R12 alignment split dropped (null).

#define KT 7
#define K2 49
#define MAX_SR 3
#define B_ 2
#define H_ 192
#define W_ 192
#define HW (H_ * W_)
#define PAD 6
#define NT 512
#define NBLOCKS 256                   // one resident block per CU; 72 iters
#define PS 17                         // patch row stride in element space
#define BUFI 280                      // swz(219)=273 -> pad to 280 ints
#define NGROUPS (B_ * H_ * W_ / 4)    // 18432
#define NITER (NGROUPS / NBLOCKS)     // 72
#define TABQ 3072                     // quads covered (>= 5*512+511 prefetch)
#define TABN (4 * TABQ)               // 12288 ints = 48KB

typedef int vint4 __attribute__((ext_vector_type(4)));

__device__ __forceinline__ int swz(int e) { return e + (e >> 2); }  // bijective

__device__ __forceinline__ int tab_entry(int jj, int cv, int offset, int d,
                                         int cvmagic) {
    if (jj >= 4 * d) jj = 4 * d - 1;            // clamp inactive tail
    int p_in = (jj >= d) + (jj >= 2 * d) + (jj >= 3 * d);
    int j  = jj - p_in * d;
    int rr = j / K2;                            // const divisor 49
    int tt = j - rr * K2;
    int ry = (rr * cvmagic) >> 16;              // rr / cv  (rr < 49)
    int rx = rr - ry * cv;
    int ty = tt / KT;                           // const divisor 7
    int tx = tt - ty * KT;
    int e = (offset + ry + ty) * PS + (offset + rx + tx) + p_in;
    return 4 * swz(e);                          // swizzled byte offset
}

__global__ __launch_bounds__(256) void tab_kernel(
    int* __restrict__ tab, int cv, int offset, int d, int cvmagic)
{
    int jj = blockIdx.x * 256 + threadIdx.x;
    if (jj < TABN) tab[jj] = tab_entry(jj, cv, offset, d, cvmagic);
}

__global__ __launch_bounds__(NT, 2) void esw_kernel(
    const float* __restrict__ in, int* __restrict__ out,
    const int* __restrict__ tab,
    int cv, int offset, int d, int cvmagic)
{
    __shared__ int patch[BUFI];                  // block-shared, one group

    const int tid = threadIdx.x;
    const int bid = blockIdx.x;
    const char* const pb = (const char*)patch;

    const int NR = (d + NT - 1) / NT;            // block-rounds per group (5)

    for (int it = 0; it < NITER; ++it) {
        const int g = it * NBLOCKS + bid;        // 256 CONSECUTIVE live groups

        // ---- stage the 13x16 neighborhood (208 ints) cooperatively ----
        if (tid < 13 * 16) {
            int dy = tid >> 4, dx = tid & 15;
            const int pix0 = 4 * g;              // W%4==0 -> group in one row
            const int b   = pix0 / HW;
            const int rem = pix0 - b * HW;
            const int h   = rem / W_;
            const int w   = rem - h * W_;
            int y = h + dy - PAD, x = w + dx - PAD;
            int v = 0;
            if ((unsigned)y < (unsigned)H_ && (unsigned)x < (unsigned)W_)
                v = (int)in[b * HW + y * W_ + x];
            patch[swz(dy * PS + dx)] = v;
        }
        asm volatile("s_waitcnt lgkmcnt(0)" ::: "memory");
        __builtin_amdgcn_sched_barrier(0);
        __builtin_amdgcn_s_barrier();            // patch visible to all 8 waves
        __builtin_amdgcn_sched_barrier(0);

        // ---- gather + store: block-round r writes 8KB contiguous ----
        int* op = out + g * (4 * d);             // <=177M ints, 32-bit safe
        if (tab) {
            vint4 t = *(const vint4*)(tab + 4 * tid);            // round 0
            #pragma unroll
            for (int r = 0; r < 5; ++r) {        // NR==5 for cv=7 (d=2401)
                if (r >= NR) break;              // guard smaller cv
                vint4 tn = *(const vint4*)(tab + 4 * (NT * (r + 1) + tid));
                int q = NT * r + tid;
                if (q < d) {                     // only last round masked
                    vint4 v;
                    v.x = *(const int*)(pb + t.x);
                    v.y = *(const int*)(pb + t.y);
                    v.z = *(const int*)(pb + t.z);
                    v.w = *(const int*)(pb + t.w);
                    *(vint4*)(op + 4 * q) = v;
                }
                t = tn;
            }
        } else {                                 // no-workspace fallback
            for (int q = tid; q < d; q += NT) {
                vint4 v;
                v.x = *(const int*)(pb + tab_entry(4 * q + 0, cv, offset, d, cvmagic));
                v.y = *(const int*)(pb + tab_entry(4 * q + 1, cv, offset, d, cvmagic));
                v.z = *(const int*)(pb + tab_entry(4 * q + 2, cv, offset, d, cvmagic));
                v.w = *(const int*)(pb + tab_entry(4 * q + 3, cv, offset, d, cvmagic));
                *(vint4*)(op + 4 * q) = v;
            }
        }
        // all waves' gathers done before next iteration's stage overwrites
        __builtin_amdgcn_sched_barrier(0);
        __builtin_amdgcn_s_barrier();
        __builtin_amdgcn_sched_barrier(0);
    }
}

extern "C" void kernel_launch(void* const* d_in, const int* in_sizes, int n_in,
                              void* d_out, int out_size, void* d_ws, size_t ws_size,
                              hipStream_t stream) {
    const float* in = (const float*)d_in[0];
    int* out = (int*)d_out;

    // out_size = B*H*W * cv^2 * 49
    int cv2 = out_size / (B_ * H_ * W_ * K2);
    int cv = 1;
    while (cv * cv < cv2) ++cv;
    int offset = MAX_SR - (cv - 1) / 2;
    int d = cv2 * K2;
    int cvmagic = 65536 / cv + 1;

    int* tab = (ws_size >= (size_t)(TABN * sizeof(int))) ? (int*)d_ws : nullptr;
    if (tab)
        tab_kernel<<<(TABN + 255) / 256, 256, 0, stream>>>(tab, cv, offset, d,
                                                           cvmagic);
    esw_kernel<<<NBLOCKS, NT, 0, stream>>>(in, out, tab, cv, offset, d, cvmagic);
}